// Round 2
// baseline (57.572 us; speedup 1.0000x reference)
//
#include <hip/hip_runtime.h>

// B=16, K=4, NQ=10, DIM=1024. U = Rx(w0) ⊗ ... ⊗ Rx(w9) @ real state.
// Gate q acts on bit (NQ-1-q) of the amplitude index (gate 0 = kron MSB).
// Output complex64: layout hypothesis this round = PLANAR (all re, then all im)
// when out_size==2*BK*DIM; real-only when out_size==BK*DIM.
constexpr int BK  = 16 * 4;
constexpr int NQ  = 10;
constexpr int DIM = 1 << NQ;  // 1024

__global__ __launch_bounds__(512)
void rx_layer_kernel(const float* __restrict__ weights,  // (BK, NQ)
                     const float* __restrict__ state,    // (BK, DIM) real
                     float* __restrict__ out_re,         // (BK, DIM)
                     float* __restrict__ out_im)         // (BK, DIM) or nullptr
{
    __shared__ float re[DIM];
    __shared__ float im[DIM];

    const int bk = blockIdx.x;
    const int t  = threadIdx.x;  // 0..511

    const float* st = state + bk * DIM;
    re[t]       = st[t];       im[t]       = 0.0f;
    re[t + 512] = st[t + 512]; im[t + 512] = 0.0f;

    const float* w = weights + bk * NQ;

    #pragma unroll
    for (int q = 0; q < NQ; ++q) {
        __syncthreads();
        const float wv = w[q];
        const float a  = cosf(0.5f * wv);
        const float b  = sinf(0.5f * wv);

        const int s  = 1 << (NQ - 1 - q);
        const int i0 = ((t & ~(s - 1)) << 1) | (t & (s - 1));
        const int i1 = i0 + s;

        const float x0r = re[i0], x0i = im[i0];
        const float x1r = re[i1], x1i = im[i1];

        re[i0] = a * x0r + b * x1i;
        im[i0] = a * x0i - b * x1r;
        re[i1] = a * x1r + b * x0i;
        im[i1] = a * x1i - b * x0r;
    }
    __syncthreads();

    float* orr = out_re + bk * DIM;
    orr[t]       = re[t];
    orr[t + 512] = re[t + 512];
    if (out_im != nullptr) {
        float* oi = out_im + bk * DIM;
        oi[t]       = im[t];
        oi[t + 512] = im[t + 512];
    }
}

extern "C" void kernel_launch(void* const* d_in, const int* in_sizes, int n_in,
                              void* d_out, int out_size, void* d_ws, size_t ws_size,
                              hipStream_t stream) {
    const float* weights = (const float*)d_in[0];  // 640 floats
    const float* state   = (const float*)d_in[1];  // 65536 floats
    float* out = (float*)d_out;

    float* out_re = out;
    float* out_im = nullptr;
    if (out_size >= 2 * BK * DIM) {
        // planar complex: [all real][all imag]
        out_im = out + BK * DIM;
    }
    rx_layer_kernel<<<BK, 512, 0, stream>>>(weights, state, out_re, out_im);
}